// Round 2
// baseline (7323.655 us; speedup 1.0000x reference)
//
#include <hip/hip_runtime.h>

#define USH unsigned short
#define AGENT __HIP_MEMORY_SCOPE_AGENT
typedef __attribute__((ext_vector_type(8))) short short8;
typedef __attribute__((ext_vector_type(4))) float f32x4;

__device__ __forceinline__ USH rne_bf16(float f){
  unsigned int u = __float_as_uint(f);
  u = (u + 0x7fffu + ((u >> 16) & 1u)) >> 16;
  return (USH)u;
}
__device__ __forceinline__ float sigm(float x){ return 1.f / (1.f + __expf(-x)); }
__device__ __forceinline__ float tanh_(float x){ return 1.f - 2.f / (__expf(2.f * x) + 1.f); }

// ---- prep: Wc = W_ih1 @ W_lin (fp32->bf16, K 34 padded to 64), bc = W_ih1@b_lin + b_ih1 + b_hh1
__global__ void k_fold(const float* __restrict__ Wih1, const float* __restrict__ Wlin,
                       const float* __restrict__ blin, const float* __restrict__ bih1,
                       const float* __restrict__ bhh1, USH* __restrict__ Wcb, float* __restrict__ bc){
  const int n = blockIdx.x;
  const int t = threadIdx.x;
  float a[34];
#pragma unroll
  for (int f = 0; f < 34; ++f) a[f] = 0.f;
  float ab = 0.f;
  for (int e = t; e < 1024; e += 64){
    const float wv = Wih1[n * 1024 + e];
    ab += wv * blin[e];
    const float* wl = Wlin + e * 34;
#pragma unroll
    for (int f = 0; f < 34; ++f) a[f] += wv * wl[f];
  }
#pragma unroll
  for (int off = 32; off > 0; off >>= 1){
    ab += __shfl_down(ab, off);
#pragma unroll
    for (int f = 0; f < 34; ++f) a[f] += __shfl_down(a[f], off);
  }
  if (t == 0){
    for (int f = 0; f < 34; ++f) Wcb[n * 64 + f] = rne_bf16(a[f]);
    for (int f = 34; f < 64; ++f) Wcb[n * 64 + f] = 0;
    bc[n] = ab + bih1[n] + bhh1[n];
  }
}

// ---- prep: weights -> bf16, b2 = b_ih2 + b_hh2
__global__ void k_convert(const float* __restrict__ Whh1, const float* __restrict__ Wih2,
                          const float* __restrict__ Whh2, const float* __restrict__ bih2,
                          const float* __restrict__ bhh2,
                          USH* __restrict__ oWhh1, USH* __restrict__ oW2a, USH* __restrict__ oW2b,
                          float* __restrict__ ob2){
  const int n = 4096 * 1024;
  for (int i = blockIdx.x * blockDim.x + threadIdx.x; i < n; i += gridDim.x * blockDim.x){
    oWhh1[i] = rne_bf16(Whh1[i]);
    oW2a[i]  = rne_bf16(Wih2[i]);
    oW2b[i]  = rne_bf16(Whh2[i]);
    if (i < 4096) ob2[i] = bih2[i] + bhh2[i];
  }
}

// ---- prep: x [B][T][34] fp32 -> xb [T][B][64] bf16 (zero-padded K)
__global__ void k_xb(const float* __restrict__ x, USH* __restrict__ xb){
  const int n = 100 * 256 * 64;
  for (int i = blockIdx.x * blockDim.x + threadIdx.x; i < n; i += gridDim.x * blockDim.x){
    const int j = i & 63;
    const int b = (i >> 6) & 255;
    const int t = i >> 14;
    xb[i] = (j < 34) ? rne_bf16(x[(b * 100 + t) * 34 + j]) : (USH)0;
  }
}

// ---- persistent kernel: 192 WGs x 512 threads; weights LDS-resident; 101 phases with grid barrier
__global__ __launch_bounds__(512) void k_persist(
    USH* __restrict__ h1b, USH* __restrict__ h2b,
    int* __restrict__ flags, int* __restrict__ ctr, float* __restrict__ part,
    const USH* __restrict__ Wcb, const float* __restrict__ bc, const float* __restrict__ b2,
    const USH* __restrict__ Whh1b, const USH* __restrict__ W2a, const USH* __restrict__ W2b,
    const USH* __restrict__ xb, float* __restrict__ out)
{
  __shared__ __attribute__((aligned(16))) char sB[131072];
  const int tid = threadIdx.x;
  const int w = tid >> 6, l = tid & 63;
  const int role = blockIdx.x >> 6;        // 0: L1,  1: L2 ih-part,  2: L2 hh-part + elementwise
  const int s = blockIdx.x & 63;
  const int col = s * 16 + (l & 15);

  // stage this WG's 64 weight rows (row-major 1024 bf16 = 128 x 16B chunks) into LDS, XOR-swizzled
  const USH* Wsrc = (role == 0) ? Whh1b : (role == 1) ? W2a : W2b;
#pragma unroll
  for (int i = 0; i < 16; ++i){
    const int q  = i * 512 + tid;
    const int rp = q >> 7, c = q & 127;
    const int gn = (rp >> 4) * 1024 + s * 16 + (rp & 15);
    const short8 v = *(const short8*)(Wsrc + (size_t)gn * 1024 + c * 8);
    *(short8*)(&sB[rp * 2048 + ((c ^ (rp & 7)) << 4)]) = v;
  }
  __syncthreads();

  float bias_i = 0.f, bias_f = 0.f, bias_g = 0.f, bias_o = 0.f;
  if (role == 0){ bias_i = bc[col]; bias_f = bc[1024 + col]; bias_g = bc[2048 + col]; bias_o = bc[3072 + col]; }
  if (role == 2){ bias_i = b2[col]; bias_f = b2[1024 + col]; bias_g = b2[2048 + col]; bias_o = b2[3072 + col]; }

  float creg[2][4];
#pragma unroll
  for (int mf = 0; mf < 2; ++mf)
#pragma unroll
    for (int r = 0; r < 4; ++r) creg[mf][r] = 0.f;

  int bi = 0;

  for (int p = 0; p <= 100; ++p){
    const bool active = (role == 0) ? (p < 100) : (p >= 1);
    if (active){
      const USH* Asrc = (role == 2) ? (h2b + (size_t)(p & 1) * 262144)
                                    : (h1b + (size_t)(p & 1) * 262144);
      const USH* xbt = xb + (size_t)p * 16384;
      const int nch = (role == 0 && p == 0) ? 0 : 16;
      const int nsteps = 2 * nch + ((role == 0) ? 2 : 0);   // always even

      f32x4 acc[2][4];
#pragma unroll
      for (int mf = 0; mf < 2; ++mf)
#pragma unroll
        for (int gq = 0; gq < 4; ++gq) acc[mf][gq] = (f32x4){0.f, 0.f, 0.f, 0.f};

      auto loadA = [&](int st, short8* af){
        const int kc = st >> 1, ks = st & 1;
        const int kk = ks * 32 + ((l >> 4) << 3);
        const USH* src; int rs;
        if (kc < nch){ src = Asrc + kc * 64 + kk; rs = 1024; }
        else         { src = xbt + kk;            rs = 64;   }
        af[0] = *(const short8*)(src + (size_t)(w * 32 +      (l & 15)) * rs);
        af[1] = *(const short8*)(src + (size_t)(w * 32 + 16 + (l & 15)) * rs);
      };
      auto loadB = [&](int st, short8* bf){
        const int kc = st >> 1, ks = st & 1;
        if (kc < nch){
          const int cI = kc * 8 + ks * 4 + (l >> 4);
#pragma unroll
          for (int gq = 0; gq < 4; ++gq){
            const int rp = gq * 16 + (l & 15);
            bf[gq] = *(const short8*)(&sB[rp * 2048 + ((cI ^ (rp & 7)) << 4)]);
          }
        } else {
          const int kk = ks * 32 + ((l >> 4) << 3);
#pragma unroll
          for (int gq = 0; gq < 4; ++gq)
            bf[gq] = *(const short8*)(Wcb + (size_t)(gq * 1024 + col) * 64 + kk);
        }
      };

      short8 a0[2], b0[4], a1[2], b1[4];
      loadA(0, a0); loadB(0, b0);
      for (int st = 0; st < nsteps; st += 2){
        loadA(st + 1, a1); loadB(st + 1, b1);
#pragma unroll
        for (int mf = 0; mf < 2; ++mf)
#pragma unroll
          for (int gq = 0; gq < 4; ++gq)
            acc[mf][gq] = __builtin_amdgcn_mfma_f32_16x16x32_bf16(a0[mf], b0[gq], acc[mf][gq], 0, 0, 0);
        if (st + 2 < nsteps){ loadA(st + 2, a0); loadB(st + 2, b0); }
#pragma unroll
        for (int mf = 0; mf < 2; ++mf)
#pragma unroll
          for (int gq = 0; gq < 4; ++gq)
            acc[mf][gq] = __builtin_amdgcn_mfma_f32_16x16x32_bf16(a1[mf], b1[gq], acc[mf][gq], 0, 0, 0);
      }

      if (role == 0){
        USH* h1n = h1b + (size_t)((p + 1) & 1) * 262144;
#pragma unroll
        for (int mf = 0; mf < 2; ++mf)
#pragma unroll
          for (int r = 0; r < 4; ++r){
            const int row = w * 32 + mf * 16 + ((l >> 4) << 2) + r;
            const float gi = acc[mf][0][r] + bias_i;
            const float gf = acc[mf][1][r] + bias_f;
            const float gg = acc[mf][2][r] + bias_g;
            const float go = acc[mf][3][r] + bias_o;
            const float cn = sigm(gf) * creg[mf][r] + sigm(gi) * tanh_(gg);
            creg[mf][r] = cn;
            h1n[row * 1024 + col] = rne_bf16(sigm(go) * tanh_(cn));
          }
      } else if (role == 1){
        float* pp = part + (size_t)s * 16384;
#pragma unroll
        for (int mf = 0; mf < 2; ++mf)
#pragma unroll
          for (int r = 0; r < 4; ++r){
            const int row = w * 32 + mf * 16 + ((l >> 4) << 2) + r;
#pragma unroll
            for (int gq = 0; gq < 4; ++gq)
              pp[row * 64 + gq * 16 + (l & 15)] = acc[mf][gq][r];
          }
        __threadfence();
        __syncthreads();
        if (tid == 0) __hip_atomic_fetch_add(&flags[s], 1, __ATOMIC_RELEASE, AGENT);
      } else {
        if (tid == 0){
          while (__hip_atomic_load(&flags[s], __ATOMIC_ACQUIRE, AGENT) < p) {}
        }
        __syncthreads();
        const float* pp = part + (size_t)s * 16384;
        USH* h2n = h2b + (size_t)((p + 1) & 1) * 262144;
#pragma unroll
        for (int mf = 0; mf < 2; ++mf)
#pragma unroll
          for (int r = 0; r < 4; ++r){
            const int row = w * 32 + mf * 16 + ((l >> 4) << 2) + r;
            const float gi = acc[mf][0][r] + pp[row * 64 +  0 + (l & 15)] + bias_i;
            const float gf = acc[mf][1][r] + pp[row * 64 + 16 + (l & 15)] + bias_f;
            const float gg = acc[mf][2][r] + pp[row * 64 + 32 + (l & 15)] + bias_g;
            const float go = acc[mf][3][r] + pp[row * 64 + 48 + (l & 15)] + bias_o;
            const float cn = sigm(gf) * creg[mf][r] + sigm(gi) * tanh_(gg);
            creg[mf][r] = cn;
            const float h = sigm(go) * tanh_(cn);
            if (p == 100){
              out[row * 1024 + col] = h;
              out[262144 + row * 1024 + col] = cn;
            } else {
              h2n[row * 1024 + col] = rne_bf16(h);
            }
          }
      }
    }

    if (p < 100){
      ++bi;
      __syncthreads();
      if (tid == 0){
        __threadfence();
        __hip_atomic_fetch_add(ctr, 1, __ATOMIC_RELEASE, AGENT);
        while (__hip_atomic_load(ctr, __ATOMIC_ACQUIRE, AGENT) < 192 * bi)
          __builtin_amdgcn_s_sleep(1);
      }
      __syncthreads();
    }
  }
}

extern "C" void kernel_launch(void* const* d_in, const int* in_sizes, int n_in,
                              void* d_out, int out_size, void* d_ws, size_t ws_size,
                              hipStream_t stream){
  const float* x    = (const float*)d_in[0];
  const float* Wlin = (const float*)d_in[1];
  const float* blin = (const float*)d_in[2];
  const float* Wih1 = (const float*)d_in[3];
  const float* Whh1 = (const float*)d_in[4];
  const float* bih1 = (const float*)d_in[5];
  const float* bhh1 = (const float*)d_in[6];
  const float* Wih2 = (const float*)d_in[7];
  const float* Whh2 = (const float*)d_in[8];
  const float* bih2 = (const float*)d_in[9];
  const float* bhh2 = (const float*)d_in[10];
  char* ws = (char*)d_ws;

  USH*   h1b   = (USH*)  (ws + 0);          // [2][256][1024] bf16
  USH*   h2b   = (USH*)  (ws + 1048576);    // [2][256][1024] bf16
  int*   flags = (int*)  (ws + 2097152);    // [64]
  int*   ctr   = (int*)  (ws + 2097664);    // [1] grid barrier counter
  float* part  = (float*)(ws + 2101248);    // [64][256][64] f32
  USH*   Wcb   = (USH*)  (ws + 6295552);    // [4096][64] bf16
  float* bc    = (float*)(ws + 6819840);    // [4096]
  float* b2    = (float*)(ws + 6836224);    // [4096]
  USH*   Whh1b = (USH*)  (ws + 6852608);    // [4096][1024] bf16
  USH*   W2a   = (USH*)  (ws + 15241216);   // W_ih2 bf16
  USH*   W2b   = (USH*)  (ws + 23629824);   // W_hh2 bf16
  USH*   xb    = (USH*)  (ws + 32018432);   // [100][256][64] bf16

  hipMemsetAsync(ws, 0, 2101248, stream);   // h1b, h2b, flags, ctr
  k_fold<<<4096, 64, 0, stream>>>(Wih1, Wlin, blin, bih1, bhh1, Wcb, bc);
  k_convert<<<4096, 256, 0, stream>>>(Whh1, Wih2, Whh2, bih2, bhh2, Whh1b, W2a, W2b, b2);
  k_xb<<<1600, 256, 0, stream>>>(x, xb);

  float* outp = (float*)d_out;
  void* args[] = {&h1b, &h2b, &flags, &ctr, &part, &Wcb, &bc, &b2,
                  &Whh1b, &W2a, &W2b, &xb, &outp};
  hipLaunchCooperativeKernel((void*)k_persist, dim3(192), dim3(512), args, 0, stream);
}

// Round 4
// 6220.850 us; speedup vs baseline: 1.1773x; 1.1773x over previous
//
#include <hip/hip_runtime.h>

#define USH unsigned short
#define AGENT __HIP_MEMORY_SCOPE_AGENT
typedef __attribute__((ext_vector_type(8))) short short8;
typedef __attribute__((ext_vector_type(4))) float f32x4;

__device__ __forceinline__ USH rne_bf16(float f){
  unsigned int u = __float_as_uint(f);
  u = (u + 0x7fffu + ((u >> 16) & 1u)) >> 16;
  return (USH)u;
}
__device__ __forceinline__ float sigm(float x){ return 1.f / (1.f + __expf(-x)); }
__device__ __forceinline__ float tanh_(float x){ return 1.f - 2.f / (__expf(2.f * x) + 1.f); }
__device__ __forceinline__ void gload16(const void* g, void* l){
  __builtin_amdgcn_global_load_lds((const __attribute__((address_space(1))) unsigned int*)g,
                                   (__attribute__((address_space(3))) unsigned int*)l, 16, 0, 0);
}
#define MFMA __builtin_amdgcn_mfma_f32_16x16x32_bf16

// ---- prep: Wc = W_ih1 @ W_lin packed frag-major, bc = W_ih1@b_lin + b_ih1 + b_hh1
__global__ void k_fold(const float* __restrict__ Wih1, const float* __restrict__ Wlin,
                       const float* __restrict__ blin, const float* __restrict__ bih1,
                       const float* __restrict__ bhh1, USH* __restrict__ Wcpk, float* __restrict__ bc){
  const int n = blockIdx.x;          // 0..4095 gate-row
  const int t = threadIdx.x;
  float a[34];
#pragma unroll
  for (int f = 0; f < 34; ++f) a[f] = 0.f;
  float ab = 0.f;
  for (int e = t; e < 1024; e += 64){
    const float wv = Wih1[n * 1024 + e];
    ab += wv * blin[e];
    const float* wl = Wlin + e * 34;
#pragma unroll
    for (int f = 0; f < 34; ++f) a[f] += wv * wl[f];
  }
#pragma unroll
  for (int off = 32; off > 0; off >>= 1){
    ab += __shfl_down(ab, off);
#pragma unroll
    for (int f = 0; f < 34; ++f) a[f] += __shfl_down(a[f], off);
  }
  if (t == 0){
    const int nc = n & 1023, gq = n >> 10, cgi = nc >> 4, lp = nc & 15;
    for (int f = 0; f < 64; ++f){
      const float v = (f < 34) ? a[f] : 0.f;
      const int lane = lp + (((f >> 3) & 3) << 4);
      const int idx = (((cgi * 2 + (f >> 5)) * 4 + gq) * 64 + lane) * 8 + (f & 7);
      Wcpk[idx] = rne_bf16(v);
    }
    bc[n] = ab + bih1[n] + bhh1[n];
  }
}

// ---- prep: pack 3 weight matrices into frag-major bf16 [cg][ks][gq][lane][8]; b2
__global__ void k_pack(const float* __restrict__ Whh1, const float* __restrict__ Wih2,
                       const float* __restrict__ Whh2, const float* __restrict__ bih2,
                       const float* __restrict__ bhh2,
                       USH* __restrict__ P1, USH* __restrict__ P2a, USH* __restrict__ P2b,
                       float* __restrict__ ob2){
  const int N = 4096 * 1024;
  for (int i = blockIdx.x * blockDim.x + threadIdx.x; i < N; i += gridDim.x * blockDim.x){
    const int j = i & 7, li = (i >> 3) & 63, gq = (i >> 9) & 3, ks = (i >> 11) & 31, cgi = i >> 16;
    const int n = gq * 1024 + cgi * 16 + (li & 15);
    const int k = ks * 32 + ((li >> 4) << 3) + j;
    const int src = n * 1024 + k;
    P1[i]  = rne_bf16(Whh1[src]);
    P2a[i] = rne_bf16(Wih2[src]);
    P2b[i] = rne_bf16(Whh2[src]);
    if (i < 4096) ob2[i] = bih2[i] + bhh2[i];
  }
}

// ---- prep: x [B][T][34] fp32 -> frag-major bf16 xp[t][g][ks2][lane][8] (K padded to 64)
__global__ void k_xpk(const float* __restrict__ x, USH* __restrict__ xp){
  const int N = 100 * 16384;
  for (int i = blockIdx.x * blockDim.x + threadIdx.x; i < N; i += gridDim.x * blockDim.x){
    const int j = i & 7, li = (i >> 3) & 63, ks = (i >> 9) & 1, g = (i >> 10) & 15, t = i >> 14;
    const int row = g * 16 + (li & 15);
    const int f = ks * 32 + ((li >> 4) << 3) + j;
    xp[i] = (f < 34) ? rne_bf16(x[(row * 100 + t) * 34 + f]) : (USH)0;
  }
}

// ---- persistent: 256 WGs x 256 thr. wg<128: L1 (cg=wg>>1, mh=wg&1); else L2.
__global__ __launch_bounds__(256) void k_persist(
    USH* __restrict__ hA1, USH* __restrict__ hA2, int* __restrict__ ctr,
    const USH* __restrict__ Wpk1, const USH* __restrict__ Wpk2a, const USH* __restrict__ Wpk2b,
    const USH* __restrict__ Wcpk, const USH* __restrict__ xpk,
    const float* __restrict__ bc, const float* __restrict__ b2, float* __restrict__ out)
{
  __shared__ __attribute__((aligned(16))) char lds[131072];
  const int tid = threadIdx.x, w = tid >> 6, l = tid & 63;
  const int wg = blockIdx.x;
  const int isL2 = wg >> 7;
  const int cg = (wg & 127) >> 1;
  const int mh = wg & 1;
  const int gb = mh * 8 + w * 2;
  const int col = cg * 16 + (l & 15);
  const int lofs16 = l * 16;
  const int lofs8 = l * 8;

  // resident LDS fill (once)
  if (!isL2){
    const USH* s = Wpk1 + (size_t)cg * 65536;              // Whh1 slice, 128 KB
#pragma unroll
    for (int r = 0; r < 32; ++r)
      gload16(s + (r * 4 + w) * 512 + lofs8, &lds[(r * 4 + w) * 1024]);
  } else {
    const USH* s = Wpk2b + (size_t)cg * 65536;             // Whh2 ks0..23, 96 KB
#pragma unroll
    for (int r = 0; r < 24; ++r)
      gload16(s + (r * 4 + w) * 512 + lofs8, &lds[(r * 4 + w) * 1024]);
  }

  // L1: Wc B-frags live in registers (2 ks x 4 gq x short8 = 32 VGPRs)
  short8 wc[2][4];
  if (!isL2){
#pragma unroll
    for (int ks = 0; ks < 2; ++ks)
#pragma unroll
      for (int gq = 0; gq < 4; ++gq)
        wc[ks][gq] = *(const short8*)(Wcpk + (size_t)cg * 4096 + (ks * 4 + gq) * 512 + lofs8);
  }
  __syncthreads();

  float bi0, bi1, bi2, bi3;
  { const float* bs = isL2 ? b2 : bc;
    bi0 = bs[col]; bi1 = bs[1024 + col]; bi2 = bs[2048 + col]; bi3 = bs[3072 + col]; }

  float creg[2][4];
#pragma unroll
  for (int mf = 0; mf < 2; ++mf)
#pragma unroll
    for (int r = 0; r < 4; ++r) creg[mf][r] = 0.f;

  const int ks2 = cg >> 1;
  const int l16 = (cg * 2 + ((l & 15) >> 3)) & 3;
  const int j2 = l & 7;

  for (int p = 0; p <= 100; ++p){
    const bool active = isL2 ? (p >= 1) : (p < 100);
    if (active){
      f32x4 acc[2][4];
#pragma unroll
      for (int mf = 0; mf < 2; ++mf)
#pragma unroll
        for (int gq = 0; gq < 4; ++gq) acc[mf][gq] = (f32x4){0.f, 0.f, 0.f, 0.f};

      if (!isL2){
        if (p > 0){
          const USH* Ap = hA1 + (size_t)((p - 1) & 1) * 262144 + gb * 16384 + lofs8;
#pragma unroll
          for (int ks = 0; ks < 32; ++ks){
            short8 a0 = *(const short8*)(Ap + ks * 512);
            short8 a1 = *(const short8*)(Ap + 16384 + ks * 512);
            const char* bb = &lds[ks * 4096 + lofs16];
#pragma unroll
            for (int gq = 0; gq < 4; ++gq){
              short8 bf = *(const short8*)(bb + gq * 1024);
              acc[0][gq] = MFMA(a0, bf, acc[0][gq], 0, 0, 0);
              acc[1][gq] = MFMA(a1, bf, acc[1][gq], 0, 0, 0);
            }
          }
        }
        const USH* Xp = xpk + (size_t)p * 16384 + gb * 1024 + lofs8;
#pragma unroll
        for (int ks = 0; ks < 2; ++ks){
          short8 a0 = *(const short8*)(Xp + ks * 512);
          short8 a1 = *(const short8*)(Xp + 1024 + ks * 512);
#pragma unroll
          for (int gq = 0; gq < 4; ++gq){
            acc[0][gq] = MFMA(a0, wc[ks][gq], acc[0][gq], 0, 0, 0);
            acc[1][gq] = MFMA(a1, wc[ks][gq], acc[1][gq], 0, 0, 0);
          }
        }
        USH* hn = hA1 + (size_t)(p & 1) * 262144;
#pragma unroll
        for (int mf = 0; mf < 2; ++mf){
          const int g2 = gb + mf;
#pragma unroll
          for (int r = 0; r < 4; ++r){
            const float gi = acc[mf][0][r] + bi0;
            const float gf = acc[mf][1][r] + bi1;
            const float gg = acc[mf][2][r] + bi2;
            const float go = acc[mf][3][r] + bi3;
            const float cn = sigm(gf) * creg[mf][r] + sigm(gi) * tanh_(gg);
            creg[mf][r] = cn;
            const int lane2 = ((l >> 4) << 2) + r + (l16 << 4);
            hn[(g2 * 32 + ks2) * 512 + lane2 * 8 + j2] = rne_bf16(sigm(go) * tanh_(cn));
          }
        }
      } else {
        const USH* A1p = hA1 + (size_t)((p - 1) & 1) * 262144 + gb * 16384 + lofs8;
        const USH* A2p = hA2 + (size_t)(p & 1) * 262144 + gb * 16384 + lofs8;
        const USH* Wsa = Wpk2a + (size_t)cg * 65536;
        const USH* Wsb = Wpk2b + (size_t)cg * 65536;
        // stage chunk 0 (Wih2 ks0..3)
#pragma unroll
        for (int r = 0; r < 4; ++r)
          gload16(Wsa + (r * 4 + w) * 512 + lofs8, &lds[98304 + (r * 4 + w) * 1024]);
        // 10 staged chunks: 0..7 = Wih2 (A=h1), 8..9 = Whh2 ks24..31 (A=h2)
#pragma unroll
        for (int c = 0; c < 10; ++c){
          __syncthreads();
          if (c < 9){
            const int t = c + 1;
            const USH* src = (t < 8) ? (Wsa + t * 8192) : (Wsb + (t - 2) * 8192);
            char* dst = &lds[98304 + (t & 1) * 16384];
#pragma unroll
            for (int r = 0; r < 4; ++r)
              gload16(src + (r * 4 + w) * 512 + lofs8, dst + (r * 4 + w) * 1024);
          }
          const char* cb = &lds[98304 + (c & 1) * 16384 + lofs16];
          const USH* Ab = (c < 8) ? A1p : A2p;
          const int ksb = (c < 8) ? c * 4 : (c - 2) * 4;
#pragma unroll
          for (int kk = 0; kk < 4; ++kk){
            const int ks = ksb + kk;
            short8 a0 = *(const short8*)(Ab + ks * 512);
            short8 a1 = *(const short8*)(Ab + 16384 + ks * 512);
#pragma unroll
            for (int gq = 0; gq < 4; ++gq){
              short8 bf = *(const short8*)(cb + kk * 4096 + gq * 1024);
              acc[0][gq] = MFMA(a0, bf, acc[0][gq], 0, 0, 0);
              acc[1][gq] = MFMA(a1, bf, acc[1][gq], 0, 0, 0);
            }
          }
        }
        // resident Whh2 ks0..23 (A=h2)
#pragma unroll
        for (int ks = 0; ks < 24; ++ks){
          short8 a0 = *(const short8*)(A2p + ks * 512);
          short8 a1 = *(const short8*)(A2p + 16384 + ks * 512);
          const char* bb = &lds[ks * 4096 + lofs16];
#pragma unroll
          for (int gq = 0; gq < 4; ++gq){
            short8 bf = *(const short8*)(bb + gq * 1024);
            acc[0][gq] = MFMA(a0, bf, acc[0][gq], 0, 0, 0);
            acc[1][gq] = MFMA(a1, bf, acc[1][gq], 0, 0, 0);
          }
        }
        if (p < 100){
          USH* hn = hA2 + (size_t)((p - 1) & 1) * 262144;
#pragma unroll
          for (int mf = 0; mf < 2; ++mf){
            const int g2 = gb + mf;
#pragma unroll
            for (int r = 0; r < 4; ++r){
              const float gi = acc[mf][0][r] + bi0;
              const float gf = acc[mf][1][r] + bi1;
              const float gg = acc[mf][2][r] + bi2;
              const float go = acc[mf][3][r] + bi3;
              const float cn = sigm(gf) * creg[mf][r] + sigm(gi) * tanh_(gg);
              creg[mf][r] = cn;
              const int lane2 = ((l >> 4) << 2) + r + (l16 << 4);
              hn[(g2 * 32 + ks2) * 512 + lane2 * 8 + j2] = rne_bf16(sigm(go) * tanh_(cn));
            }
          }
        } else {
#pragma unroll
          for (int mf = 0; mf < 2; ++mf){
#pragma unroll
            for (int r = 0; r < 4; ++r){
              const int row = (gb + mf) * 16 + ((l >> 4) << 2) + r;
              const float gi = acc[mf][0][r] + bi0;
              const float gf = acc[mf][1][r] + bi1;
              const float gg = acc[mf][2][r] + bi2;
              const float go = acc[mf][3][r] + bi3;
              const float cn = sigm(gf) * creg[mf][r] + sigm(gi) * tanh_(gg);
              out[row * 1024 + col] = sigm(go) * tanh_(cn);
              out[262144 + row * 1024 + col] = cn;
            }
          }
        }
      }
    }
    if (p < 100){
      __syncthreads();
      if (tid == 0){
        __threadfence();
        __hip_atomic_fetch_add(ctr, 1, __ATOMIC_RELEASE, AGENT);
        while (__hip_atomic_load(ctr, __ATOMIC_ACQUIRE, AGENT) < 256 * (p + 1))
          __builtin_amdgcn_s_sleep(1);
      }
      __syncthreads();
    }
  }
}

extern "C" void kernel_launch(void* const* d_in, const int* in_sizes, int n_in,
                              void* d_out, int out_size, void* d_ws, size_t ws_size,
                              hipStream_t stream){
  const float* x    = (const float*)d_in[0];
  const float* Wlin = (const float*)d_in[1];
  const float* blin = (const float*)d_in[2];
  const float* Wih1 = (const float*)d_in[3];
  const float* Whh1 = (const float*)d_in[4];
  const float* bih1 = (const float*)d_in[5];
  const float* bhh1 = (const float*)d_in[6];
  const float* Wih2 = (const float*)d_in[7];
  const float* Whh2 = (const float*)d_in[8];
  const float* bih2 = (const float*)d_in[9];
  const float* bhh2 = (const float*)d_in[10];
  char* ws = (char*)d_ws;

  USH*   hA2   = (USH*)  (ws + 0);          // [2][16][32][64][8] bf16, zeroed
  int*   ctr   = (int*)  (ws + 1048576);    // barrier counter, zeroed
  USH*   hA1   = (USH*)  (ws + 1049600);
  USH*   Wpk1  = (USH*)  (ws + 2098176);    // 8 MB each
  USH*   Wpk2a = (USH*)  (ws + 10486784);
  USH*   Wpk2b = (USH*)  (ws + 18875392);
  USH*   Wcpk  = (USH*)  (ws + 27264000);   // 512 KB
  USH*   xpk   = (USH*)  (ws + 27788288);   // 3.2 MB
  float* bc    = (float*)(ws + 31065088);
  float* b2    = (float*)(ws + 31081472);

  hipMemsetAsync(ws, 0, 1048580, stream);   // hA2 + ctr
  k_fold<<<4096, 64, 0, stream>>>(Wih1, Wlin, blin, bih1, bhh1, Wcpk, bc);
  k_pack<<<2048, 256, 0, stream>>>(Whh1, Wih2, Whh2, bih2, bhh2, Wpk1, Wpk2a, Wpk2b, b2);
  k_xpk<<<1024, 256, 0, stream>>>(x, xpk);

  float* outp = (float*)d_out;
  void* args[] = {&hA1, &hA2, &ctr, &Wpk1, &Wpk2a, &Wpk2b, &Wcpk, &xpk, &bc, &b2, &outp};
  hipError_t e = hipLaunchCooperativeKernel((void*)k_persist, dim3(256), dim3(256), args, 0, stream);
  if (e != hipSuccess){
    // fallback: plain launch — 256 WGs at 1 WG/CU are co-resident on 256 CUs
    k_persist<<<dim3(256), dim3(256), 0, stream>>>(hA1, hA2, ctr, Wpk1, Wpk2a, Wpk2b,
                                                   Wcpk, xpk, bc, b2, outp);
  }
}

// Round 5
// 2706.800 us; speedup vs baseline: 2.7057x; 2.2982x over previous
//
#include <hip/hip_runtime.h>

#define USH unsigned short
#define AGENT __HIP_MEMORY_SCOPE_AGENT
typedef __attribute__((ext_vector_type(8))) short short8;
typedef __attribute__((ext_vector_type(4))) float f32x4;

__device__ __forceinline__ USH rne_bf16(float f){
  unsigned int u = __float_as_uint(f);
  u = (u + 0x7fffu + ((u >> 16) & 1u)) >> 16;
  return (USH)u;
}
__device__ __forceinline__ float sigm(float x){ return 1.f / (1.f + __expf(-x)); }
__device__ __forceinline__ float tanh_(float x){ return 1.f - 2.f / (__expf(2.f * x) + 1.f); }
__device__ __forceinline__ void gload16(const void* g, void* l){
  __builtin_amdgcn_global_load_lds((const __attribute__((address_space(1))) unsigned int*)g,
                                   (__attribute__((address_space(3))) unsigned int*)l, 16, 0, 0);
}
#define MFMA __builtin_amdgcn_mfma_f32_16x16x32_bf16

// ---- prep: Wc = W_ih1 @ W_lin packed frag-major, bc = W_ih1@b_lin + b_ih1 + b_hh1
__global__ void k_fold(const float* __restrict__ Wih1, const float* __restrict__ Wlin,
                       const float* __restrict__ blin, const float* __restrict__ bih1,
                       const float* __restrict__ bhh1, USH* __restrict__ Wcpk, float* __restrict__ bc){
  const int n = blockIdx.x;          // 0..4095 gate-row
  const int t = threadIdx.x;
  float a[34];
#pragma unroll
  for (int f = 0; f < 34; ++f) a[f] = 0.f;
  float ab = 0.f;
  for (int e = t; e < 1024; e += 64){
    const float wv = Wih1[n * 1024 + e];
    ab += wv * blin[e];
    const float* wl = Wlin + e * 34;
#pragma unroll
    for (int f = 0; f < 34; ++f) a[f] += wv * wl[f];
  }
#pragma unroll
  for (int off = 32; off > 0; off >>= 1){
    ab += __shfl_down(ab, off);
#pragma unroll
    for (int f = 0; f < 34; ++f) a[f] += __shfl_down(a[f], off);
  }
  if (t == 0){
    const int nc = n & 1023, gq = n >> 10, cgi = nc >> 4, lp = nc & 15;
    for (int f = 0; f < 64; ++f){
      const float v = (f < 34) ? a[f] : 0.f;
      const int lane = lp + (((f >> 3) & 3) << 4);
      const int idx = (((cgi * 2 + (f >> 5)) * 4 + gq) * 64 + lane) * 8 + (f & 7);
      Wcpk[idx] = rne_bf16(v);
    }
    bc[n] = ab + bih1[n] + bhh1[n];
  }
}

// ---- prep: pack 3 weight matrices into frag-major bf16 [cg][ks][gq][lane][8]; b2
__global__ void k_pack(const float* __restrict__ Whh1, const float* __restrict__ Wih2,
                       const float* __restrict__ Whh2, const float* __restrict__ bih2,
                       const float* __restrict__ bhh2,
                       USH* __restrict__ P1, USH* __restrict__ P2a, USH* __restrict__ P2b,
                       float* __restrict__ ob2){
  const int N = 4096 * 1024;
  for (int i = blockIdx.x * blockDim.x + threadIdx.x; i < N; i += gridDim.x * blockDim.x){
    const int j = i & 7, li = (i >> 3) & 63, gq = (i >> 9) & 3, ks = (i >> 11) & 31, cgi = i >> 16;
    const int n = gq * 1024 + cgi * 16 + (li & 15);
    const int k = ks * 32 + ((li >> 4) << 3) + j;
    const int src = n * 1024 + k;
    P1[i]  = rne_bf16(Whh1[src]);
    P2a[i] = rne_bf16(Wih2[src]);
    P2b[i] = rne_bf16(Whh2[src]);
    if (i < 4096) ob2[i] = bih2[i] + bhh2[i];
  }
}

// ---- prep: x [B][T][34] fp32 -> frag-major bf16 xp[t][g][ks2][lane][8] (K padded to 64)
__global__ void k_xpk(const float* __restrict__ x, USH* __restrict__ xp){
  const int N = 100 * 16384;
  for (int i = blockIdx.x * blockDim.x + threadIdx.x; i < N; i += gridDim.x * blockDim.x){
    const int j = i & 7, li = (i >> 3) & 63, ks = (i >> 9) & 1, g = (i >> 10) & 15, t = i >> 14;
    const int row = g * 16 + (li & 15);
    const int f = ks * 32 + ((li >> 4) << 3) + j;
    xp[i] = (f < 34) ? rne_bf16(x[(row * 100 + t) * 34 + f]) : (USH)0;
  }
}

// ---- persistent: 256 WGs x 256 thr. wg<128: L1 (cg=wg>>1, mh=wg&1); else L2.
__global__ __launch_bounds__(256) void k_persist(
    USH* __restrict__ hA1, USH* __restrict__ hA2,
    int* __restrict__ ctrA, int* __restrict__ ctrB,
    const USH* __restrict__ Wpk1, const USH* __restrict__ Wpk2a, const USH* __restrict__ Wpk2b,
    const USH* __restrict__ Wcpk, const USH* __restrict__ xpk,
    const float* __restrict__ bc, const float* __restrict__ b2, float* __restrict__ out)
{
  __shared__ __attribute__((aligned(16))) char lds[131072];
  const int tid = threadIdx.x, w = tid >> 6, l = tid & 63;
  const int wg = blockIdx.x;
  const int isL2 = wg >> 7;
  const int cg = (wg & 127) >> 1;
  const int mh = wg & 1;
  const int gb = mh * 8 + w * 2;
  const int col = cg * 16 + (l & 15);
  const int lofs16 = l * 16;
  const int lofs8 = l * 8;

  // resident LDS fill (once)
  if (!isL2){
    const USH* s = Wpk1 + (size_t)cg * 65536;              // Whh1 slice, 128 KB
#pragma unroll
    for (int r = 0; r < 32; ++r)
      gload16(s + (r * 4 + w) * 512 + lofs8, &lds[(r * 4 + w) * 1024]);
  } else {
    const USH* s = Wpk2b + (size_t)cg * 65536;             // Whh2 ks0..23, 96 KB
#pragma unroll
    for (int r = 0; r < 24; ++r)
      gload16(s + (r * 4 + w) * 512 + lofs8, &lds[(r * 4 + w) * 1024]);
  }

  // L1: Wc B-frags live in registers (2 ks x 4 gq x short8 = 32 VGPRs)
  short8 wc[2][4];
  if (!isL2){
#pragma unroll
    for (int ks = 0; ks < 2; ++ks)
#pragma unroll
      for (int gq = 0; gq < 4; ++gq)
        wc[ks][gq] = *(const short8*)(Wcpk + (size_t)cg * 4096 + (ks * 4 + gq) * 512 + lofs8);
  }
  __syncthreads();

  float bi0, bi1, bi2, bi3;
  { const float* bs = isL2 ? b2 : bc;
    bi0 = bs[col]; bi1 = bs[1024 + col]; bi2 = bs[2048 + col]; bi3 = bs[3072 + col]; }

  float creg[2][4];
#pragma unroll
  for (int mf = 0; mf < 2; ++mf)
#pragma unroll
    for (int r = 0; r < 4; ++r) creg[mf][r] = 0.f;

  const int ks2 = cg >> 1;
  const int l16 = (cg * 2 + ((l & 15) >> 3)) & 3;
  const int j2 = l & 7;

  for (int p = 0; p <= 100; ++p){
    const bool active = isL2 ? (p >= 1) : (p < 100);
    if (active){
      f32x4 acc[2][4];
#pragma unroll
      for (int mf = 0; mf < 2; ++mf)
#pragma unroll
        for (int gq = 0; gq < 4; ++gq) acc[mf][gq] = (f32x4){0.f, 0.f, 0.f, 0.f};

      if (!isL2){
        if (p > 0){
          const USH* Ap = hA1 + (size_t)((p - 1) % 3) * 262144 + gb * 16384 + lofs8;
#pragma unroll
          for (int ks = 0; ks < 32; ++ks){
            short8 a0 = *(const short8*)(Ap + ks * 512);
            short8 a1 = *(const short8*)(Ap + 16384 + ks * 512);
            const char* bb = &lds[ks * 4096 + lofs16];
#pragma unroll
            for (int gq = 0; gq < 4; ++gq){
              short8 bf = *(const short8*)(bb + gq * 1024);
              acc[0][gq] = MFMA(a0, bf, acc[0][gq], 0, 0, 0);
              acc[1][gq] = MFMA(a1, bf, acc[1][gq], 0, 0, 0);
            }
          }
        }
        const USH* Xp = xpk + (size_t)p * 16384 + gb * 1024 + lofs8;
#pragma unroll
        for (int ks = 0; ks < 2; ++ks){
          short8 a0 = *(const short8*)(Xp + ks * 512);
          short8 a1 = *(const short8*)(Xp + 1024 + ks * 512);
#pragma unroll
          for (int gq = 0; gq < 4; ++gq){
            acc[0][gq] = MFMA(a0, wc[ks][gq], acc[0][gq], 0, 0, 0);
            acc[1][gq] = MFMA(a1, wc[ks][gq], acc[1][gq], 0, 0, 0);
          }
        }
        USH* hn = hA1 + (size_t)(p % 3) * 262144;
#pragma unroll
        for (int mf = 0; mf < 2; ++mf){
          const int g2 = gb + mf;
#pragma unroll
          for (int r = 0; r < 4; ++r){
            const float gi = acc[mf][0][r] + bi0;
            const float gf = acc[mf][1][r] + bi1;
            const float gg = acc[mf][2][r] + bi2;
            const float go = acc[mf][3][r] + bi3;
            const float cn = sigm(gf) * creg[mf][r] + sigm(gi) * tanh_(gg);
            creg[mf][r] = cn;
            const int lane2 = ((l >> 4) << 2) + r + (l16 << 4);
            hn[(g2 * 32 + ks2) * 512 + lane2 * 8 + j2] = rne_bf16(sigm(go) * tanh_(cn));
          }
        }
      } else {
        const USH* A1p = hA1 + (size_t)((p - 1) % 3) * 262144 + gb * 16384 + lofs8;
        const USH* A2p = hA2 + (size_t)(p & 1) * 262144 + gb * 16384 + lofs8;
        const USH* Wsa = Wpk2a + (size_t)cg * 65536;
        const USH* Wsb = Wpk2b + (size_t)cg * 65536;
        // chunks 0..7 = Wih2 (A=h1), 8..9 = Whh2 ks24..31 (A=h2)
        short8 ar[2][8];
        // preload chunk 0: LDS staging + A-regs
#pragma unroll
        for (int r = 0; r < 4; ++r)
          gload16(Wsa + (r * 4 + w) * 512 + lofs8, &lds[98304 + (r * 4 + w) * 1024]);
#pragma unroll
        for (int kk = 0; kk < 4; ++kk){
          ar[0][kk * 2]     = *(const short8*)(A1p + kk * 512);
          ar[0][kk * 2 + 1] = *(const short8*)(A1p + 16384 + kk * 512);
        }
#pragma unroll
        for (int c = 0; c < 10; ++c){
          __syncthreads();                     // chunk c staging + A-regs complete
          if (c < 9){
            const int t = c + 1;
            const USH* src = (t < 8) ? (Wsa + t * 8192) : (Wsb + (t - 2) * 8192);
            char* dst = &lds[98304 + (t & 1) * 16384];
#pragma unroll
            for (int r = 0; r < 4; ++r)
              gload16(src + (r * 4 + w) * 512 + lofs8, dst + (r * 4 + w) * 1024);
            const USH* Ab = (t < 8) ? A1p : A2p;
            const int ksb = (t < 8) ? t * 4 : (t - 2) * 4;
#pragma unroll
            for (int kk = 0; kk < 4; ++kk){
              ar[t & 1][kk * 2]     = *(const short8*)(Ab + (ksb + kk) * 512);
              ar[t & 1][kk * 2 + 1] = *(const short8*)(Ab + 16384 + (ksb + kk) * 512);
            }
          }
          const char* cb = &lds[98304 + (c & 1) * 16384 + lofs16];
#pragma unroll
          for (int kk = 0; kk < 4; ++kk){
#pragma unroll
            for (int gq = 0; gq < 4; ++gq){
              short8 bf = *(const short8*)(cb + kk * 4096 + gq * 1024);
              acc[0][gq] = MFMA(ar[c & 1][kk * 2],     bf, acc[0][gq], 0, 0, 0);
              acc[1][gq] = MFMA(ar[c & 1][kk * 2 + 1], bf, acc[1][gq], 0, 0, 0);
            }
          }
        }
        // resident Whh2 ks0..23 (A=h2)
#pragma unroll
        for (int ks = 0; ks < 24; ++ks){
          short8 a0 = *(const short8*)(A2p + ks * 512);
          short8 a1 = *(const short8*)(A2p + 16384 + ks * 512);
          const char* bb = &lds[ks * 4096 + lofs16];
#pragma unroll
          for (int gq = 0; gq < 4; ++gq){
            short8 bf = *(const short8*)(bb + gq * 1024);
            acc[0][gq] = MFMA(a0, bf, acc[0][gq], 0, 0, 0);
            acc[1][gq] = MFMA(a1, bf, acc[1][gq], 0, 0, 0);
          }
        }
        if (p < 100){
          USH* hn = hA2 + (size_t)((p - 1) & 1) * 262144;
#pragma unroll
          for (int mf = 0; mf < 2; ++mf){
            const int g2 = gb + mf;
#pragma unroll
            for (int r = 0; r < 4; ++r){
              const float gi = acc[mf][0][r] + bi0;
              const float gf = acc[mf][1][r] + bi1;
              const float gg = acc[mf][2][r] + bi2;
              const float go = acc[mf][3][r] + bi3;
              const float cn = sigm(gf) * creg[mf][r] + sigm(gi) * tanh_(gg);
              creg[mf][r] = cn;
              const int lane2 = ((l >> 4) << 2) + r + (l16 << 4);
              hn[(g2 * 32 + ks2) * 512 + lane2 * 8 + j2] = rne_bf16(sigm(go) * tanh_(cn));
            }
          }
        } else {
#pragma unroll
          for (int mf = 0; mf < 2; ++mf){
#pragma unroll
            for (int r = 0; r < 4; ++r){
              const int row = (gb + mf) * 16 + ((l >> 4) << 2) + r;
              const float gi = acc[mf][0][r] + bi0;
              const float gf = acc[mf][1][r] + bi1;
              const float gg = acc[mf][2][r] + bi2;
              const float go = acc[mf][3][r] + bi3;
              const float cn = sigm(gf) * creg[mf][r] + sigm(gi) * tanh_(gg);
              out[row * 1024 + col] = sigm(go) * tanh_(cn);
              out[262144 + row * 1024 + col] = cn;
            }
          }
        }
      }
    }
    if (p < 100){
      __syncthreads();                          // all WG stores write-acked (vmcnt drained)
      if (tid == 0){
        __builtin_amdgcn_fence(__ATOMIC_RELEASE, "agent");      // single wbl2: flush my XCD
        __hip_atomic_fetch_add(isL2 ? ctrB : ctrA, 1, __ATOMIC_RELAXED, AGENT);
        const int q = p + 1;
        const int tA = 128 * q;
        const int tB = isL2 ? 128 * q : 128 * (q - 1);          // L1 may run 1 phase ahead
        while (__hip_atomic_load(ctrA, __ATOMIC_RELAXED, AGENT) < tA)
          __builtin_amdgcn_s_sleep(2);
        while (__hip_atomic_load(ctrB, __ATOMIC_RELAXED, AGENT) < tB)
          __builtin_amdgcn_s_sleep(2);
        __builtin_amdgcn_fence(__ATOMIC_ACQUIRE, "agent");      // single inv: drop stale lines
      }
      __syncthreads();
    }
  }
}

extern "C" void kernel_launch(void* const* d_in, const int* in_sizes, int n_in,
                              void* d_out, int out_size, void* d_ws, size_t ws_size,
                              hipStream_t stream){
  const float* x    = (const float*)d_in[0];
  const float* Wlin = (const float*)d_in[1];
  const float* blin = (const float*)d_in[2];
  const float* Wih1 = (const float*)d_in[3];
  const float* Whh1 = (const float*)d_in[4];
  const float* bih1 = (const float*)d_in[5];
  const float* bhh1 = (const float*)d_in[6];
  const float* Wih2 = (const float*)d_in[7];
  const float* Whh2 = (const float*)d_in[8];
  const float* bih2 = (const float*)d_in[9];
  const float* bhh2 = (const float*)d_in[10];
  char* ws = (char*)d_ws;

  USH*   hA2   = (USH*)  (ws + 0);          // [2][16][32][64][8] bf16, zeroed
  int*   ctrA  = (int*)  (ws + 1048576);    // L1 completions, zeroed
  int*   ctrB  = (int*)  (ws + 1048704);    // L2 completions, zeroed (own cacheline)
  USH*   hA1   = (USH*)  (ws + 1049600);    // [3][16][32][64][8] bf16 (triple buffer)
  USH*   Wpk1  = (USH*)  (ws + 2622464);    // 8 MB each
  USH*   Wpk2a = (USH*)  (ws + 11011072);
  USH*   Wpk2b = (USH*)  (ws + 19399680);
  USH*   Wcpk  = (USH*)  (ws + 27788288);   // 512 KB
  USH*   xpk   = (USH*)  (ws + 28312576);   // 3.2 MB
  float* bc    = (float*)(ws + 31589376);
  float* b2    = (float*)(ws + 31605760);

  hipMemsetAsync(ws, 0, 1048832, stream);   // hA2 + ctrA + ctrB
  k_fold<<<4096, 64, 0, stream>>>(Wih1, Wlin, blin, bih1, bhh1, Wcpk, bc);
  k_pack<<<2048, 256, 0, stream>>>(Whh1, Wih2, Whh2, bih2, bhh2, Wpk1, Wpk2a, Wpk2b, b2);
  k_xpk<<<1024, 256, 0, stream>>>(x, xpk);

  float* outp = (float*)d_out;
  void* args[] = {&hA1, &hA2, &ctrA, &ctrB, &Wpk1, &Wpk2a, &Wpk2b, &Wcpk, &xpk, &bc, &b2, &outp};
  hipError_t e = hipLaunchCooperativeKernel((void*)k_persist, dim3(256), dim3(256), args, 0, stream);
  if (e != hipSuccess){
    // fallback: plain launch — 256 WGs at 1 WG/CU are co-resident on 256 CUs
    k_persist<<<dim3(256), dim3(256), 0, stream>>>(hA1, hA2, ctrA, ctrB, Wpk1, Wpk2a, Wpk2b,
                                                   Wcpk, xpk, bc, b2, outp);
  }
}

// Round 6
// 1759.732 us; speedup vs baseline: 4.1618x; 1.5382x over previous
//
#include <hip/hip_runtime.h>

#define USH unsigned short
#define AGENT __HIP_MEMORY_SCOPE_AGENT
typedef __attribute__((ext_vector_type(8))) short short8;
typedef __attribute__((ext_vector_type(4))) float f32x4;

__device__ __forceinline__ USH rne_bf16(float f){
  unsigned int u = __float_as_uint(f);
  u = (u + 0x7fffu + ((u >> 16) & 1u)) >> 16;
  return (USH)u;
}
__device__ __forceinline__ float sigm(float x){ return 1.f / (1.f + __expf(-x)); }
__device__ __forceinline__ float tanh_(float x){ return 1.f - 2.f / (__expf(2.f * x) + 1.f); }
__device__ __forceinline__ void gload16(const void* g, void* l){
  __builtin_amdgcn_global_load_lds((const __attribute__((address_space(1))) unsigned int*)g,
                                   (__attribute__((address_space(3))) unsigned int*)l, 16, 0, 0);
}
// agent-coherent (write-through past XCD L2) 2-byte store
__device__ __forceinline__ void st_bf16_sc1(USH* p, USH v){
  asm volatile("global_store_short %0, %1, off sc1" :: "v"(p), "v"((unsigned int)v) : "memory");
}
#define MFMA __builtin_amdgcn_mfma_f32_16x16x32_bf16

// ---- prep: Wc = W_ih1 @ W_lin packed frag-major, bc = W_ih1@b_lin + b_ih1 + b_hh1
__global__ void k_fold(const float* __restrict__ Wih1, const float* __restrict__ Wlin,
                       const float* __restrict__ blin, const float* __restrict__ bih1,
                       const float* __restrict__ bhh1, USH* __restrict__ Wcpk, float* __restrict__ bc){
  const int n = blockIdx.x;          // 0..4095 gate-row
  const int t = threadIdx.x;
  float a[34];
#pragma unroll
  for (int f = 0; f < 34; ++f) a[f] = 0.f;
  float ab = 0.f;
  for (int e = t; e < 1024; e += 64){
    const float wv = Wih1[n * 1024 + e];
    ab += wv * blin[e];
    const float* wl = Wlin + e * 34;
#pragma unroll
    for (int f = 0; f < 34; ++f) a[f] += wv * wl[f];
  }
#pragma unroll
  for (int off = 32; off > 0; off >>= 1){
    ab += __shfl_down(ab, off);
#pragma unroll
    for (int f = 0; f < 34; ++f) a[f] += __shfl_down(a[f], off);
  }
  if (t == 0){
    const int nc = n & 1023, gq = n >> 10, cgi = nc >> 4, lp = nc & 15;
    for (int f = 0; f < 64; ++f){
      const float v = (f < 34) ? a[f] : 0.f;
      const int lane = lp + (((f >> 3) & 3) << 4);
      const int idx = (((cgi * 2 + (f >> 5)) * 4 + gq) * 64 + lane) * 8 + (f & 7);
      Wcpk[idx] = rne_bf16(v);
    }
    bc[n] = ab + bih1[n] + bhh1[n];
  }
}

// ---- prep: pack 3 weight matrices into frag-major bf16 [cg][ks][gq][lane][8]; b2
__global__ void k_pack(const float* __restrict__ Whh1, const float* __restrict__ Wih2,
                       const float* __restrict__ Whh2, const float* __restrict__ bih2,
                       const float* __restrict__ bhh2,
                       USH* __restrict__ P1, USH* __restrict__ P2a, USH* __restrict__ P2b,
                       float* __restrict__ ob2){
  const int N = 4096 * 1024;
  for (int i = blockIdx.x * blockDim.x + threadIdx.x; i < N; i += gridDim.x * blockDim.x){
    const int j = i & 7, li = (i >> 3) & 63, gq = (i >> 9) & 3, ks = (i >> 11) & 31, cgi = i >> 16;
    const int n = gq * 1024 + cgi * 16 + (li & 15);
    const int k = ks * 32 + ((li >> 4) << 3) + j;
    const int src = n * 1024 + k;
    P1[i]  = rne_bf16(Whh1[src]);
    P2a[i] = rne_bf16(Wih2[src]);
    P2b[i] = rne_bf16(Whh2[src]);
    if (i < 4096) ob2[i] = bih2[i] + bhh2[i];
  }
}

// ---- prep: x [B][T][34] fp32 -> frag-major bf16 xp[t][g][ks2][lane][8] (K padded to 64)
__global__ void k_xpk(const float* __restrict__ x, USH* __restrict__ xp){
  const int N = 100 * 16384;
  for (int i = blockIdx.x * blockDim.x + threadIdx.x; i < N; i += gridDim.x * blockDim.x){
    const int j = i & 7, li = (i >> 3) & 63, ks = (i >> 9) & 1, g = (i >> 10) & 15, t = i >> 14;
    const int row = g * 16 + (li & 15);
    const int f = ks * 32 + ((li >> 4) << 3) + j;
    xp[i] = (f < 34) ? rne_bf16(x[(row * 100 + t) * 34 + f]) : (USH)0;
  }
}

// ---- persistent: 256 WGs x 256 thr. wg<128: L1 (cg=wg>>1, mh=wg&1); else L2.
__global__ __launch_bounds__(256) void k_persist(
    USH* __restrict__ hA1, USH* __restrict__ hA2,
    int* __restrict__ ctrA, int* __restrict__ ctrB,
    const USH* __restrict__ Wpk1, const USH* __restrict__ Wpk2a, const USH* __restrict__ Wpk2b,
    const USH* __restrict__ Wcpk, const USH* __restrict__ xpk,
    const float* __restrict__ bc, const float* __restrict__ b2, float* __restrict__ out,
    int d1, int d2, int useFence)
{
  __shared__ __attribute__((aligned(16))) char lds[131072];
  const int tid = threadIdx.x, w = tid >> 6, l = tid & 63;
  const int wg = blockIdx.x;
  const int isL2 = wg >> 7;
  const int cg = (wg & 127) >> 1;
  const int mh = wg & 1;
  const int gb = mh * 8 + w * 2;
  const int col = cg * 16 + (l & 15);
  const int lofs16 = l * 16;
  const int lofs8 = l * 8;

  // resident LDS fill (once)
  if (!isL2){
    const USH* s = Wpk1 + (size_t)cg * 65536;              // Whh1 slice, 128 KB
#pragma unroll
    for (int r = 0; r < 32; ++r)
      gload16(s + (r * 4 + w) * 512 + lofs8, &lds[(r * 4 + w) * 1024]);
  } else {
    const USH* s = Wpk2b + (size_t)cg * 65536;             // Whh2 ks0..23, 96 KB
#pragma unroll
    for (int r = 0; r < 24; ++r)
      gload16(s + (r * 4 + w) * 512 + lofs8, &lds[(r * 4 + w) * 1024]);
  }

  // L1: Wc B-frags live in registers (2 ks x 4 gq x short8 = 32 VGPRs)
  short8 wc[2][4];
  if (!isL2){
#pragma unroll
    for (int ks = 0; ks < 2; ++ks)
#pragma unroll
      for (int gq = 0; gq < 4; ++gq)
        wc[ks][gq] = *(const short8*)(Wcpk + (size_t)cg * 4096 + (ks * 4 + gq) * 512 + lofs8);
  }
  __syncthreads();

  float bi0, bi1, bi2, bi3;
  { const float* bs = isL2 ? b2 : bc;
    bi0 = bs[col]; bi1 = bs[1024 + col]; bi2 = bs[2048 + col]; bi3 = bs[3072 + col]; }

  float creg[2][4];
#pragma unroll
  for (int mf = 0; mf < 2; ++mf)
#pragma unroll
    for (int r = 0; r < 4; ++r) creg[mf][r] = 0.f;

  const int ks2 = cg >> 1;
  const int l16 = (cg * 2 + ((l & 15) >> 3)) & 3;
  const int j2 = l & 7;

  for (int p = 0; p <= 100; ++p){
    const bool active = isL2 ? (p >= 1) : (p < 100);
    if (active){
      f32x4 acc[2][4];
#pragma unroll
      for (int mf = 0; mf < 2; ++mf)
#pragma unroll
        for (int gq = 0; gq < 4; ++gq) acc[mf][gq] = (f32x4){0.f, 0.f, 0.f, 0.f};

      if (!isL2){
        if (p > 0){
          const USH* Ap = hA1 + (size_t)((p - 1) % d1) * 262144 + gb * 16384 + lofs8;
#pragma unroll
          for (int ks = 0; ks < 32; ++ks){
            short8 a0 = *(const short8*)(Ap + ks * 512);
            short8 a1 = *(const short8*)(Ap + 16384 + ks * 512);
            const char* bb = &lds[ks * 4096 + lofs16];
#pragma unroll
            for (int gq = 0; gq < 4; ++gq){
              short8 bf = *(const short8*)(bb + gq * 1024);
              acc[0][gq] = MFMA(a0, bf, acc[0][gq], 0, 0, 0);
              acc[1][gq] = MFMA(a1, bf, acc[1][gq], 0, 0, 0);
            }
          }
        }
        const USH* Xp = xpk + (size_t)p * 16384 + gb * 1024 + lofs8;
#pragma unroll
        for (int ks = 0; ks < 2; ++ks){
          short8 a0 = *(const short8*)(Xp + ks * 512);
          short8 a1 = *(const short8*)(Xp + 1024 + ks * 512);
#pragma unroll
          for (int gq = 0; gq < 4; ++gq){
            acc[0][gq] = MFMA(a0, wc[ks][gq], acc[0][gq], 0, 0, 0);
            acc[1][gq] = MFMA(a1, wc[ks][gq], acc[1][gq], 0, 0, 0);
          }
        }
        USH* hn = hA1 + (size_t)(p % d1) * 262144;
#pragma unroll
        for (int mf = 0; mf < 2; ++mf){
          const int g2 = gb + mf;
#pragma unroll
          for (int r = 0; r < 4; ++r){
            const float gi = acc[mf][0][r] + bi0;
            const float gf = acc[mf][1][r] + bi1;
            const float gg = acc[mf][2][r] + bi2;
            const float go = acc[mf][3][r] + bi3;
            const float cn = sigm(gf) * creg[mf][r] + sigm(gi) * tanh_(gg);
            creg[mf][r] = cn;
            const int lane2 = ((l >> 4) << 2) + r + (l16 << 4);
            st_bf16_sc1(&hn[(g2 * 32 + ks2) * 512 + lane2 * 8 + j2], rne_bf16(sigm(go) * tanh_(cn)));
          }
        }
      } else {
        const USH* A1p = hA1 + (size_t)((p - 1) % d1) * 262144 + gb * 16384 + lofs8;
        const USH* A2p = hA2 + (size_t)((p - 1) % d2) * 262144 + gb * 16384 + lofs8;
        const USH* Wsa = Wpk2a + (size_t)cg * 65536;
        const USH* Wsb = Wpk2b + (size_t)cg * 65536;
        // chunks 0..7 = Wih2 (A=h1), 8..9 = Whh2 ks24..31 (A=h2)
        short8 ar[2][8];
        // preload chunk 0: LDS staging + A-regs
#pragma unroll
        for (int r = 0; r < 4; ++r)
          gload16(Wsa + (r * 4 + w) * 512 + lofs8, &lds[98304 + (r * 4 + w) * 1024]);
#pragma unroll
        for (int kk = 0; kk < 4; ++kk){
          ar[0][kk * 2]     = *(const short8*)(A1p + kk * 512);
          ar[0][kk * 2 + 1] = *(const short8*)(A1p + 16384 + kk * 512);
        }
#pragma unroll
        for (int c = 0; c < 10; ++c){
          __syncthreads();                     // chunk c staging + A-regs complete
          if (c < 9){
            const int t = c + 1;
            const USH* src = (t < 8) ? (Wsa + t * 8192) : (Wsb + (t - 2) * 8192);
            char* dst = &lds[98304 + (t & 1) * 16384];
#pragma unroll
            for (int r = 0; r < 4; ++r)
              gload16(src + (r * 4 + w) * 512 + lofs8, dst + (r * 4 + w) * 1024);
            const USH* Ab = (t < 8) ? A1p : A2p;
            const int ksb = (t < 8) ? t * 4 : (t - 2) * 4;
#pragma unroll
            for (int kk = 0; kk < 4; ++kk){
              ar[t & 1][kk * 2]     = *(const short8*)(Ab + (ksb + kk) * 512);
              ar[t & 1][kk * 2 + 1] = *(const short8*)(Ab + 16384 + (ksb + kk) * 512);
            }
          }
          const char* cb = &lds[98304 + (c & 1) * 16384 + lofs16];
#pragma unroll
          for (int kk = 0; kk < 4; ++kk){
#pragma unroll
            for (int gq = 0; gq < 4; ++gq){
              short8 bf = *(const short8*)(cb + kk * 4096 + gq * 1024);
              acc[0][gq] = MFMA(ar[c & 1][kk * 2],     bf, acc[0][gq], 0, 0, 0);
              acc[1][gq] = MFMA(ar[c & 1][kk * 2 + 1], bf, acc[1][gq], 0, 0, 0);
            }
          }
        }
        // resident Whh2 ks0..23 (A=h2)
#pragma unroll
        for (int ks = 0; ks < 24; ++ks){
          short8 a0 = *(const short8*)(A2p + ks * 512);
          short8 a1 = *(const short8*)(A2p + 16384 + ks * 512);
          const char* bb = &lds[ks * 4096 + lofs16];
#pragma unroll
          for (int gq = 0; gq < 4; ++gq){
            short8 bf = *(const short8*)(bb + gq * 1024);
            acc[0][gq] = MFMA(a0, bf, acc[0][gq], 0, 0, 0);
            acc[1][gq] = MFMA(a1, bf, acc[1][gq], 0, 0, 0);
          }
        }
        if (p < 100){
          USH* hn = hA2 + (size_t)(p % d2) * 262144;
#pragma unroll
          for (int mf = 0; mf < 2; ++mf){
            const int g2 = gb + mf;
#pragma unroll
            for (int r = 0; r < 4; ++r){
              const float gi = acc[mf][0][r] + bi0;
              const float gf = acc[mf][1][r] + bi1;
              const float gg = acc[mf][2][r] + bi2;
              const float go = acc[mf][3][r] + bi3;
              const float cn = sigm(gf) * creg[mf][r] + sigm(gi) * tanh_(gg);
              creg[mf][r] = cn;
              const int lane2 = ((l >> 4) << 2) + r + (l16 << 4);
              st_bf16_sc1(&hn[(g2 * 32 + ks2) * 512 + lane2 * 8 + j2], rne_bf16(sigm(go) * tanh_(cn)));
            }
          }
        } else {
#pragma unroll
          for (int mf = 0; mf < 2; ++mf){
#pragma unroll
            for (int r = 0; r < 4; ++r){
              const int row = (gb + mf) * 16 + ((l >> 4) << 2) + r;
              const float gi = acc[mf][0][r] + bi0;
              const float gf = acc[mf][1][r] + bi1;
              const float gg = acc[mf][2][r] + bi2;
              const float go = acc[mf][3][r] + bi3;
              const float cn = sigm(gf) * creg[mf][r] + sigm(gi) * tanh_(gg);
              out[row * 1024 + col] = sigm(go) * tanh_(cn);
              out[262144 + row * 1024 + col] = cn;
            }
          }
        }
      }
    }
    if (p < 100){
      asm volatile("s_waitcnt vmcnt(0)" ::: "memory");   // drain sc1 h-stores (asm-hidden)
      __syncthreads();
      if (tid == 0){
        if (useFence) __builtin_amdgcn_fence(__ATOMIC_RELEASE, "agent");
        __hip_atomic_fetch_add(isL2 ? ctrB : ctrA, 1, __ATOMIC_RELAXED, AGENT);
        const int q = p + 1;
        const int tA = 128 * q;
        const int tB = isL2 ? 128 * q : 128 * (q - 1);    // L1 may run 1 phase ahead
        while (__hip_atomic_load(ctrA, __ATOMIC_RELAXED, AGENT) < tA)
          __builtin_amdgcn_s_sleep(1);
        while (__hip_atomic_load(ctrB, __ATOMIC_RELAXED, AGENT) < tB)
          __builtin_amdgcn_s_sleep(1);
        if (useFence) __builtin_amdgcn_fence(__ATOMIC_ACQUIRE, "agent");
      }
      __syncthreads();
    }
  }
}

extern "C" void kernel_launch(void* const* d_in, const int* in_sizes, int n_in,
                              void* d_out, int out_size, void* d_ws, size_t ws_size,
                              hipStream_t stream){
  const float* x    = (const float*)d_in[0];
  const float* Wlin = (const float*)d_in[1];
  const float* blin = (const float*)d_in[2];
  const float* Wih1 = (const float*)d_in[3];
  const float* Whh1 = (const float*)d_in[4];
  const float* bih1 = (const float*)d_in[5];
  const float* bhh1 = (const float*)d_in[6];
  const float* Wih2 = (const float*)d_in[7];
  const float* Whh2 = (const float*)d_in[8];
  const float* bih2 = (const float*)d_in[9];
  const float* bhh2 = (const float*)d_in[10];
  char* ws = (char*)d_ws;

  const size_t SLOT = 524288;
  int d1 = 100, d2 = 100, useFence = 0;
  const size_t need = 1024 + 200 * SLOT + 3 * 8388608ull + 524288 + 3276800 + 32768;
  if (ws_size < need){ d1 = 3; d2 = 2; useFence = 1; }   // fallback: round-5 fenced scheme

  size_t off = 0;
  int*   ctrA  = (int*)(ws + off);  off += 128;
  int*   ctrB  = (int*)(ws + off);  off = 1024;
  USH*   hA2   = (USH*)(ws + off);  off += (size_t)d2 * SLOT;
  USH*   hA1   = (USH*)(ws + off);  off += (size_t)d1 * SLOT;
  USH*   Wpk1  = (USH*)(ws + off);  off += 8388608;
  USH*   Wpk2a = (USH*)(ws + off);  off += 8388608;
  USH*   Wpk2b = (USH*)(ws + off);  off += 8388608;
  USH*   Wcpk  = (USH*)(ws + off);  off += 524288;
  USH*   xpk   = (USH*)(ws + off);  off += 3276800;
  float* bc    = (float*)(ws + off); off += 16384;
  float* b2    = (float*)(ws + off);

  hipMemsetAsync(ws, 0, 1024 + 2 * SLOT, stream);        // ctrs + h2 slots 0..1
  k_fold<<<4096, 64, 0, stream>>>(Wih1, Wlin, blin, bih1, bhh1, Wcpk, bc);
  k_pack<<<2048, 256, 0, stream>>>(Whh1, Wih2, Whh2, bih2, bhh2, Wpk1, Wpk2a, Wpk2b, b2);
  k_xpk<<<1024, 256, 0, stream>>>(x, xpk);

  float* outp = (float*)d_out;
  void* args[] = {&hA1, &hA2, &ctrA, &ctrB, &Wpk1, &Wpk2a, &Wpk2b, &Wcpk, &xpk, &bc, &b2, &outp,
                  &d1, &d2, &useFence};
  hipError_t e = hipLaunchCooperativeKernel((void*)k_persist, dim3(256), dim3(256), args, 0, stream);
  if (e != hipSuccess){
    k_persist<<<dim3(256), dim3(256), 0, stream>>>(hA1, hA2, ctrA, ctrB, Wpk1, Wpk2a, Wpk2b,
                                                   Wcpk, xpk, bc, b2, outp, d1, d2, useFence);
  }
}